// Round 1
// baseline (217.846 us; speedup 1.0000x reference)
//
#include <hip/hip_runtime.h>
#include <math.h>

#define NROWS 131072
#define M 8
#define D 128
#define ROWS_PER_BLOCK 128
#define E_CONST 2.71828182845904523536f

__global__ __launch_bounds__(256) void emma_fused_kernel(
    const float* __restrict__ x, const float* __restrict__ q,
    const float* __restrict__ w, const float* __restrict__ b,
    const float* __restrict__ gammas, const float* __restrict__ G,
    const float* __restrict__ bias, const float* __restrict__ qmin,
    float* __restrict__ out)
{
    __shared__ float s_beta[ROWS_PER_BLOCK][M];
    __shared__ float s_g[M][M];
    __shared__ float s_w[M], s_b[M], s_G[M], s_bias[M], s_qmin[M];

    const int tid = threadIdx.x;

    // Load tiny parameter tensors into LDS.
    if (tid < M * M) {
        int i = tid >> 3, j = tid & 7;
        // symmetrized gamma: g[i,j] = gammas[min(i,j), max(i,j)]
        s_g[i][j] = (i < j) ? gammas[i * M + j] : gammas[j * M + i];
    }
    if (tid >= 64 && tid < 64 + M) {
        int m = tid - 64;
        s_w[m]    = w[m];
        s_b[m]    = b[m];
        s_G[m]    = G[m];
        s_bias[m] = bias[m];
        s_qmin[m] = qmin[m];
    }
    __syncthreads();

    const int row0 = blockIdx.x * ROWS_PER_BLOCK;

    // ---- Phase 1: threads 0..ROWS_PER_BLOCK-1 compute betas for one row each
    if (tid < ROWS_PER_BLOCK) {
        const int n = row0 + tid;
        const float4 q0 = *reinterpret_cast<const float4*>(q + (size_t)n * M);
        const float4 q1 = *reinterpret_cast<const float4*>(q + (size_t)n * M + 4);
        float qv[M] = {q0.x, q0.y, q0.z, q0.w, q1.x, q1.y, q1.z, q1.w};

        float lphi[M];
        #pragma unroll
        for (int m = 0; m < M; ++m) {
            float corr = fmaxf(qv[m] - s_qmin[m] + E_CONST, E_CONST);
            float phi  = (1.0f + s_w[m]) * corr + s_b[m];
            lphi[m] = logf(phi);   // phi >= e > 0 always
        }

        // modal[i] = sum_j phi_i^g * phi_j^(1-g) = sum_j exp(g*lphi_i + (1-g)*lphi_j)
        float modal[M];
        #pragma unroll
        for (int i = 0; i < M; ++i) {
            float s = 0.0f;
            #pragma unroll
            for (int j = 0; j < M; ++j) {
                float g = s_g[i][j];
                s += expf(fmaf(g, lphi[i] - lphi[j], lphi[j]));
            }
            modal[i] = s;
        }

        // alphas = softmax(-modal)  (TAU = 1)
        float mx = -modal[0];
        #pragma unroll
        for (int i = 1; i < M; ++i) mx = fmaxf(mx, -modal[i]);
        float esum = 0.0f;
        float ea[M];
        #pragma unroll
        for (int i = 0; i < M; ++i) {
            ea[i] = expf(-modal[i] - mx);
            esum += ea[i];
        }
        float inv = 1.0f / esum;

        // betas = relu(tanh(G*alpha + bias))
        #pragma unroll
        for (int m = 0; m < M; ++m) {
            float alpha = ea[m] * inv;
            float t = tanhf(fmaf(s_G[m], alpha, s_bias[m]));
            s_beta[tid][m] = fmaxf(t, 0.0f);
        }
    }
    __syncthreads();

    // ---- Phase 2: stream x -> out, scaled by beta. 256 float4 per row.
    const size_t base = (size_t)row0 * (M * D);
    const float4* __restrict__ x4 = reinterpret_cast<const float4*>(x + base);
    float4* __restrict__ o4       = reinterpret_cast<float4*>(out + base);
    const int mm = tid >> 5;  // which mode this thread's float4 belongs to

    #pragma unroll 4
    for (int r = 0; r < ROWS_PER_BLOCK; ++r) {
        const float beta = s_beta[r][mm];
        float4 v = x4[(size_t)r * 256 + tid];
        v.x *= beta; v.y *= beta; v.z *= beta; v.w *= beta;
        o4[(size_t)r * 256 + tid] = v;
    }
}

extern "C" void kernel_launch(void* const* d_in, const int* in_sizes, int n_in,
                              void* d_out, int out_size, void* d_ws, size_t ws_size,
                              hipStream_t stream) {
    const float* x      = (const float*)d_in[0];
    const float* q      = (const float*)d_in[1];
    const float* w      = (const float*)d_in[2];
    const float* b      = (const float*)d_in[3];
    const float* gammas = (const float*)d_in[4];
    const float* G      = (const float*)d_in[5];
    const float* bias   = (const float*)d_in[6];
    const float* qmin   = (const float*)d_in[7];
    float* out = (float*)d_out;

    const int grid = NROWS / ROWS_PER_BLOCK;  // 1024 blocks
    emma_fused_kernel<<<grid, 256, 0, stream>>>(x, q, w, b, gammas, G, bias, qmin, out);
}